// Round 7
// baseline (177.495 us; speedup 1.0000x reference)
//
#include <hip/hip_runtime.h>

#define B_ 2
#define S_ 2048
#define D_ 1024
#define H_ 16
#define DK_ 64
#define M_ (B_ * S_)   // 4096
#define N_ (3 * D_)    // 3072

typedef __bf16 bf16x8 __attribute__((ext_vector_type(8)));
typedef short s8vec __attribute__((ext_vector_type(8)));
typedef float f4vec __attribute__((ext_vector_type(4)));

static __device__ __forceinline__ ushort f2b(float f) {
  union { float f; unsigned u; } v; v.f = f;
  unsigned u = v.u;
  u += 0x7FFFu + ((u >> 16) & 1u);   // RNE to bf16
  return (ushort)(u >> 16);
}

static __device__ __forceinline__ unsigned pk2(float a, float b) {
#if __has_builtin(__builtin_amdgcn_cvt_pk_bf16_f32)
  typedef __bf16 b2 __attribute__((ext_vector_type(2)));
  b2 r = __builtin_amdgcn_cvt_pk_bf16_f32(a, b);
  return __builtin_bit_cast(unsigned, r);
#else
  return (unsigned)f2b(a) | ((unsigned)f2b(b) << 16);
#endif
}

static __device__ __forceinline__ float fexp2(float x) {
#if __has_builtin(__builtin_amdgcn_exp2f)
  return __builtin_amdgcn_exp2f(x);
#else
  return exp2f(x);
#endif
}

static __device__ __forceinline__ f4vec mfma16(s8vec a, s8vec b, f4vec c) {
  return __builtin_amdgcn_mfma_f32_16x16x32_bf16(
      __builtin_bit_cast(bf16x8, a), __builtin_bit_cast(bf16x8, b), c, 0, 0, 0);
}

static __device__ __forceinline__ void gl_lds16(const ushort* g, ushort* l) {
  __builtin_amdgcn_global_load_lds(
      (const __attribute__((address_space(1))) unsigned*)g,
      (__attribute__((address_space(3))) unsigned*)l, 16, 0, 0);
}

// raw workgroup barrier draining LDS only; in-flight global->VGPR loads cross it
static __device__ __forceinline__ void wg_barrier_lds() {
  asm volatile("" ::: "memory");
  __builtin_amdgcn_s_waitcnt(0xC07F);   // vmcnt(63) expcnt(7) lgkmcnt(0)
  __builtin_amdgcn_s_barrier();
  asm volatile("" ::: "memory");
}

// ---- merged conversion kernel: blocks [0,4096) do x, [4096,4864) do W ----
__global__ __launch_bounds__(256) void cvt_all(const float* __restrict__ x,
                                               const float* __restrict__ Wq,
                                               const float* __restrict__ Wk,
                                               const float* __restrict__ Wv,
                                               ushort* __restrict__ xb,
                                               ushort* __restrict__ wbt) {
  const int t = threadIdx.x;
  if (blockIdx.x < 4096) {
    int i = blockIdx.x * 256 + t;
    float4 v = ((const float4*)x)[i];
    ushort4 o;
    o.x = f2b(v.x); o.y = f2b(v.y); o.z = f2b(v.z); o.w = f2b(v.w);
    ((ushort4*)xb)[i] = o;
  } else {
    __shared__ ushort T[64 * 72];
    int bid = blockIdx.x - 4096;            // 0..767: (w, h, d-tile)
    int w = bid >> 8, rem = bid & 255;
    int h = rem >> 4, d0 = (rem & 15) * 64;
    const float* W = (w == 0) ? Wq : (w == 1) ? Wk : Wv;
    const float* src = W + (size_t)h * 65536 + (size_t)d0 * 64;   // [64 d][64 k]
#pragma unroll
    for (int j = 0; j < 4; ++j) {
      int idx = j * 256 + t;
      int dr = idx >> 4, kc = (idx & 15) * 4;
      float4 v = *(const float4*)(src + dr * 64 + kc);
      T[(kc + 0) * 72 + dr] = f2b(v.x);
      T[(kc + 1) * 72 + dr] = f2b(v.y);
      T[(kc + 2) * 72 + dr] = f2b(v.z);
      T[(kc + 3) * 72 + dr] = f2b(v.w);
    }
    __syncthreads();
    const int kk = t >> 2, dcg = (t & 3) * 16;
    ushort* dst = wbt + ((size_t)w * 1024 + h * 64 + kk) * 1024 + d0 + dcg;
    *(s8vec*)dst       = *(const s8vec*)&T[kk * 72 + dcg];
    *(s8vec*)(dst + 8) = *(const s8vec*)&T[kk * 72 + dcg + 8];
  }
}

// ---- fused QKV projection: C[4096][3072] = X[4096][1024] @ Wbt^T (m97 structure) ----
// Q output pre-scaled by log2(e) so attn uses raw exp2.  (unchanged control)
__global__ __launch_bounds__(256) void proj_gemm(const ushort* __restrict__ xb,
                                                 const ushort* __restrict__ wbt,
                                                 ushort* __restrict__ qkv) {
  __shared__ __attribute__((aligned(16))) ushort As[128 * 64];
  __shared__ __attribute__((aligned(16))) ushort Bs[128 * 64];
  const int tid = threadIdx.x, wid = tid >> 6, lane = tid & 63;
  const int quad = lane >> 4, l15 = lane & 15;
  const int wm = wid & 1, wn = wid >> 1;
  const int m0 = blockIdx.x * 128, n0 = blockIdx.y * 128;

  f4vec acc[4][4];
#pragma unroll
  for (int mb = 0; mb < 4; mb++)
#pragma unroll
    for (int nb = 0; nb < 4; nb++)
#pragma unroll
      for (int i = 0; i < 4; i++) acc[mb][nb][i] = 0.f;

  const int sr = tid >> 3, sg = tid & 7;
  const int lg = sg ^ (sr & 7);
  const ushort* Ab = xb + (size_t)m0 * D_;
  const ushort* Bb = wbt + (size_t)n0 * D_;

  for (int k0 = 0; k0 < D_; k0 += 64) {
    __syncthreads();
#pragma unroll
    for (int j = 0; j < 4; ++j) {
      int r = j * 32 + sr;
      gl_lds16(Ab + (size_t)r * D_ + k0 + lg * 8, &As[j * 2048 + wid * 512]);
      gl_lds16(Bb + (size_t)r * D_ + k0 + lg * 8, &Bs[j * 2048 + wid * 512]);
    }
    __syncthreads();

#pragma unroll
    for (int kb = 0; kb < 2; ++kb) {
      s8vec af[4], bf[4];
#pragma unroll
      for (int mb = 0; mb < 4; ++mb) {
        int m = wm * 64 + mb * 16 + l15;
        int gpos = (kb * 4 + quad) ^ (m & 7);
        af[mb] = *(const s8vec*)&As[m * 64 + gpos * 8];
      }
#pragma unroll
      for (int nb = 0; nb < 4; ++nb) {
        int n = wn * 64 + nb * 16 + l15;
        int gpos = (kb * 4 + quad) ^ (n & 7);
        bf[nb] = *(const s8vec*)&Bs[n * 64 + gpos * 8];
      }
#pragma unroll
      for (int mb = 0; mb < 4; ++mb)
#pragma unroll
        for (int nb = 0; nb < 4; ++nb)
          acc[mb][nb] = mfma16(af[mb], bf[nb], acc[mb][nb]);
    }
  }

  const size_t per = (size_t)B_ * H_ * S_ * DK_;
  const int w = n0 >> 10;
  if (w == 2) {
    ushort* vt = qkv + 2 * per;
#pragma unroll
    for (int mb = 0; mb < 4; ++mb)
#pragma unroll
      for (int nb = 0; nb < 4; ++nb)
#pragma unroll
        for (int i = 0; i < 4; ++i) {
          int m = m0 + wm * 64 + mb * 16 + quad * 4 + i;
          int b = m >> 11, s = m & 2047;
          int n1 = (n0 & 1023) + wn * 64 + nb * 16 + l15;
          vt[((size_t)b * 1024 + n1) * S_ + s] = f2b(acc[mb][nb][i]);
        }
  } else {
    const float qs = (w == 0) ? 1.44269504f : 1.0f;   // log2(e) pre-scale
#pragma unroll
    for (int mb = 0; mb < 4; ++mb)
#pragma unroll
      for (int nb = 0; nb < 4; ++nb)
#pragma unroll
        for (int i = 0; i < 4; ++i) {
          int m = m0 + wm * 64 + mb * 16 + quad * 4 + i;
          int b = m >> 11, s = m & 2047;
          int n1 = (n0 & 1023) + wn * 64 + nb * 16 + l15;
          qkv[(size_t)w * per + (((size_t)b * H_ + (n1 >> 6)) * S_ + s) * 64 + (n1 & 63)] =
              f2b(acc[mb][nb][i] * qs);
        }
  }
}

// ---- flash attention v5: 256 thr, 4 waves x 32 Q-rows (Q-tile 128), K-tile 64.
// S^T trick: compute S^T = K·Q^T (swapped mfma operands, same LDS reads) so
// P^T lands with 4 consecutive keys/lane -> b64 P-writes, and Ps[q][key]
// unpadded-128 is exactly the PV fragment layout (O^T = V^T·P^T).
// LDS 48KB -> 3 blocks/CU residency.
__global__ __launch_bounds__(256) void attn(const ushort* __restrict__ qg,
                                            const ushort* __restrict__ kg,
                                            const ushort* __restrict__ vtg,
                                            float* __restrict__ out) {
  __shared__ __attribute__((aligned(16))) ushort Ks[64 * 64];      // [key][d], chunk-XOR
  __shared__ __attribute__((aligned(16))) ushort Vt[64 * 64];      // [dv][key], chunk-XOR
  __shared__ __attribute__((aligned(16))) ushort Ps[4][32 * 128];  // [q][key], chunk-XOR by q&7
  const int qt = blockIdx.x, bh = blockIdx.y;
  const int b = bh >> 4, h = bh & 15;
  const int tid = threadIdx.x, wid = tid >> 6, lane = tid & 63;
  const int quad = lane >> 4, l15 = lane & 15, l7 = l15 & 7;

  // Q fragments (B-operand content: B[k=d][n=q] == Q[q=l15(+16mb)][d=kb*32+quad*8+j])
  const ushort* qbase = qg + ((size_t)bh * S_ + qt * 128 + wid * 32) * DK_;
  s8vec aq[2][2];
#pragma unroll
  for (int mb = 0; mb < 2; mb++) {
    aq[mb][0] = *(const s8vec*)(qbase + (size_t)(mb * 16 + l15) * DK_ + quad * 8);
    aq[mb][1] = *(const s8vec*)(qbase + (size_t)(mb * 16 + l15) * DK_ + 32 + quad * 8);
  }

  f4vec o[2][4];          // O^T[dv=nb*16+quad*4+i][q=mb*16+l15]
  float lsum[2];
#pragma unroll
  for (int mb = 0; mb < 2; mb++) {
    lsum[mb] = 0.f;
#pragma unroll
    for (int nb = 0; nb < 4; nb++)
#pragma unroll
      for (int i = 0; i < 4; i++) o[mb][nb][i] = 0.f;
  }

  // staging: thread t -> rows {r, r+32} of K and of V^T; chunk slot gs
  const int r = tid >> 3, gs = tid & 7;
  const int gk = gs ^ (r & 7);             // (r+32)&7 == r&7
  const ushort* kb_ = kg + (size_t)bh * S_ * DK_;
  const ushort* vb_ = vtg + (size_t)bh * 64 * S_;

  s8vec kpre[2], vpre[2];
  kpre[0] = *(const s8vec*)(kb_ + (size_t)r * DK_ + gk * 8);
  kpre[1] = *(const s8vec*)(kb_ + (size_t)(r + 32) * DK_ + gk * 8);
  vpre[0] = *(const s8vec*)(vb_ + (size_t)r * S_ + gk * 8);
  vpre[1] = *(const s8vec*)(vb_ + (size_t)(r + 32) * S_ + gk * 8);

  for (int kt = 0; kt < S_ / 64; ++kt) {
    wg_barrier_lds();                      // readers of previous tile done
    *(s8vec*)&Ks[r * 64 + gs * 8]        = kpre[0];   // vmcnt auto-waits
    *(s8vec*)&Ks[(r + 32) * 64 + gs * 8] = kpre[1];
    *(s8vec*)&Vt[r * 64 + gs * 8]        = vpre[0];
    *(s8vec*)&Vt[(r + 32) * 64 + gs * 8] = vpre[1];
    if (kt + 1 < S_ / 64) {               // prefetch next tile; stays in flight
      const ushort* kn = kb_ + (size_t)((kt + 1) * 64 + r) * DK_ + gk * 8;
      kpre[0] = *(const s8vec*)(kn);
      kpre[1] = *(const s8vec*)(kn + (size_t)32 * DK_);
      const ushort* vn = vb_ + (size_t)r * S_ + (kt + 1) * 64 + gk * 8;
      vpre[0] = *(const s8vec*)(vn);
      vpre[1] = *(const s8vec*)(vn + (size_t)32 * S_);
    }
    wg_barrier_lds();                      // staging writes visible

    // S^T = K Q^T : A-frag = Ks rows (m=key), B = Q regs (n=q). Same reads as before.
    f4vec sct[2][4];
#pragma unroll
    for (int nb = 0; nb < 4; nb++) {
      const int row = nb * 16 + l15;
      s8vec ak0 = *(const s8vec*)&Ks[row * 64 + ((0 + quad) ^ l7) * 8];
      s8vec ak1 = *(const s8vec*)&Ks[row * 64 + ((4 + quad) ^ l7) * 8];
#pragma unroll
      for (int mb = 0; mb < 2; mb++) {
        f4vec z;
#pragma unroll
        for (int i = 0; i < 4; i++) z[i] = 0.f;
        z = mfma16(ak0, aq[mb][0], z);
        sct[mb][nb] = mfma16(ak1, aq[mb][1], z);
      }
    }

    // softmax: exp2 (Q pre-scaled), pack 4 consecutive keys -> one b64 LDS write
#pragma unroll
    for (int mb = 0; mb < 2; mb++) {
      const int q = mb * 16 + l15;
#pragma unroll
      for (int nb = 0; nb < 4; nb++) {
#pragma unroll
        for (int i = 0; i < 4; i++) {
          float p = fexp2(sct[mb][nb][i]);
          sct[mb][nb][i] = p;
          lsum[mb] += p;
        }
        unsigned p01 = pk2(sct[mb][nb][0], sct[mb][nb][1]);
        unsigned p23 = pk2(sct[mb][nb][2], sct[mb][nb][3]);
        // key = nb*16 + quad*4 + i; chunk c = nb*2+(quad>>1), swizzle c^(q&7)
        const int c = (nb * 2 + (quad >> 1)) ^ l7;
        *(uint2*)&Ps[wid][q * 128 + c * 8 + (quad & 1) * 4] = make_uint2(p01, p23);
      }
    }
    // no barrier: Ps[wid] per-wave (intra-wave lgkm ordering suffices)

    // O^T += V^T P^T : A-frag = Vt rows (m=dv), B-frag = Ps rows (n=q)
#pragma unroll
    for (int kc = 0; kc < 2; kc++) {
      s8vec ap[2];
#pragma unroll
      for (int mb = 0; mb < 2; mb++)
        ap[mb] = *(const s8vec*)&Ps[wid][(mb * 16 + l15) * 128 + (((kc * 4 + quad)) ^ l7) * 8];
#pragma unroll
      for (int nb = 0; nb < 4; nb++) {
        s8vec av = *(const s8vec*)&Vt[(nb * 16 + l15) * 64 + ((kc * 4 + quad) ^ l7) * 8];
        o[0][nb] = mfma16(av, ap[0], o[0][nb]);
        o[1][nb] = mfma16(av, ap[1], o[1][nb]);
      }
    }
  }

  // reduce lsum over the 4 quads holding each q (lanes l15, +16, +32, +48)
#pragma unroll
  for (int mb = 0; mb < 2; mb++) {
    lsum[mb] += __shfl_xor(lsum[mb], 16, 64);
    lsum[mb] += __shfl_xor(lsum[mb], 32, 64);
  }

  // epilogue: O^T -> out[b][s=q][h*64+dv], float4 (full 64B lines)
#pragma unroll
  for (int mb = 0; mb < 2; mb++) {
    const float inv = 1.0f / lsum[mb];
    float* ob = out + ((size_t)b * S_ + qt * 128 + wid * 32 + mb * 16 + l15) * D_ + h * DK_;
#pragma unroll
    for (int nb = 0; nb < 4; nb++) {
      float4 v;
      v.x = o[mb][nb][0] * inv;
      v.y = o[mb][nb][1] * inv;
      v.z = o[mb][nb][2] * inv;
      v.w = o[mb][nb][3] * inv;
      *(float4*)(ob + nb * 16 + quad * 4) = v;
    }
  }
}

extern "C" void kernel_launch(void* const* d_in, const int* in_sizes, int n_in,
                              void* d_out, int out_size, void* d_ws, size_t ws_size,
                              hipStream_t stream) {
  const float* x  = (const float*)d_in[0];
  const float* Wq = (const float*)d_in[1];
  const float* Wk = (const float*)d_in[2];
  const float* Wv = (const float*)d_in[3];
  float* out = (float*)d_out;

  ushort* xb  = (ushort*)d_ws;                       // B*S*D bf16
  ushort* wbt = xb + (size_t)B_ * S_ * D_;           // [3072][1024] bf16
  ushort* qkv = wbt + (size_t)3 * D_ * D_;           // q,k: [b][h][s][64]; v: [b*1024+n1][s]
  const size_t per = (size_t)B_ * H_ * S_ * DK_;

  cvt_all<<<4096 + 768, 256, 0, stream>>>(x, Wq, Wk, Wv, xb, wbt);
  proj_gemm<<<dim3(M_ / 128, N_ / 128), 256, 0, stream>>>(xb, wbt, qkv);
  attn<<<dim3(S_ / 128, B_ * H_), 256, 0, stream>>>(qkv, qkv + per, qkv + 2 * per, out);
}